// Round 7
// baseline (17251.378 us; speedup 1.0000x reference)
//
#include <hip/hip_runtime.h>
#include <hip/hip_bf16.h>
#include <stdint.h>

#define BATCH 4096
#define UNITS 1024
#define NSTEP 128

typedef __attribute__((ext_vector_type(4))) float f32x4;
typedef __attribute__((ext_vector_type(8))) short s16x8;

__device__ __forceinline__ void gload16(const void* g, void* l) {
  __builtin_amdgcn_global_load_lds(
      (const __attribute__((address_space(1))) unsigned int*)g,
      (__attribute__((address_space(3))) unsigned int*)l, 16, 0, 0);
}

__device__ __forceinline__ void block_barrier() {
  asm volatile("" ::: "memory");
  __builtin_amdgcn_s_barrier();
  asm volatile("" ::: "memory");
}

__device__ __forceinline__ float fsigmoid(float x) {
  return 1.0f / (1.0f + __expf(-x));
}
__device__ __forceinline__ float ftanh(float x) {
  return 1.0f - 2.0f / (__expf(2.0f * x) + 1.0f);
}

// 16-MFMA quadrant cluster; MO/GO must be literals (static acc indexing).
#define MMA(Afr, Bfr, MO, GO)                                              \
  do {                                                                     \
    __builtin_amdgcn_s_setprio(1);                                         \
    _Pragma("unroll") for (int m_ = 0; m_ < 4; ++m_)                       \
    _Pragma("unroll") for (int g_ = 0; g_ < 2; ++g_)                       \
    _Pragma("unroll") for (int k_ = 0; k_ < 2; ++k_)                       \
        acc[(MO) + m_][(GO) + g_] =                                        \
            __builtin_amdgcn_mfma_f32_16x16x32_bf16(                       \
                Afr[m_][k_], Bfr[g_][k_], acc[(MO) + m_][(GO) + g_],       \
                0, 0, 0);                                                  \
    __builtin_amdgcn_s_setprio(0);                                         \
  } while (0)

// Transpose recurrent_kernel [1024][4096] f32 -> permuted bf16 [4096][1024].
// orig n = g*1024 + u, u = q*64 + wc*16 + ul
//   -> n' = q*256 + (g>>1)*128 + wc*32 + (g&1)*16 + ul
// (gate-pair = contiguous 128-row staging half; gates lane-local in epilogue)
// Rt0 = plain R; Rt1 = R + dense_w (x) kernel (autoregressive fold).
__global__ void prep_weights(const float* __restrict__ R,
                             const float* __restrict__ ker,   // [4096]
                             const float* __restrict__ dw,    // [1024]
                             __hip_bfloat16* __restrict__ Rt0,
                             __hip_bfloat16* __restrict__ Rt1) {
  __shared__ float tile[32][33];
  __shared__ float dws[32];
  const int n0 = blockIdx.x * 32;
  const int k0 = blockIdx.y * 32;
  const int tx = threadIdx.x;       // 0..31
  const int ty = threadIdx.y;       // 0..7
#pragma unroll
  for (int i = 0; i < 4; ++i) {
    int k = ty + i * 8;
    tile[k][tx] = R[(size_t)(k0 + k) * 4096 + n0 + tx];
  }
  if (ty == 0) dws[tx] = dw[k0 + tx];
  __syncthreads();
#pragma unroll
  for (int i = 0; i < 4; ++i) {
    int n = ty + i * 8;
    float v = tile[tx][n];
    int gn = n0 + n, gk = k0 + tx;
    int g = gn >> 10, u = gn & 1023;
    int q = u >> 6, wc = (u >> 4) & 3, ul = u & 15;
    int np = q * 256 + (g >> 1) * 128 + wc * 32 + (g & 1) * 16 + ul;
    size_t o = (size_t)np * 1024 + gk;
    Rt0[o] = __float2bfloat16(v);
    Rt1[o] = __float2bfloat16(v + dws[tx] * ker[gn]);
  }
}

__global__ void prep_state(const float* __restrict__ feat,   // [4096][512]
                           const float* __restrict__ bias,   // [4096]
                           const float* __restrict__ ker,    // [4096]
                           const float* __restrict__ db,     // [1]
                           float* __restrict__ bias1,
                           __hip_bfloat16* __restrict__ hA,
                           float* __restrict__ c,
                           float* __restrict__ out) {
  const int total = BATCH * UNITS;
  const float dbv = db[0];
  for (int i = blockIdx.x * blockDim.x + threadIdx.x; i < total;
       i += gridDim.x * blockDim.x) {
    int b = i >> 10, u = i & 1023;
    float v = feat[b * 512 + (u & 511)];   // concat([features,features])
    hA[i] = __float2bfloat16(v);
    c[i] = v;
    if (i < 4096) bias1[i] = bias[i] + dbv * ker[i];
    if (i < BATCH * NSTEP) out[i] = dbv;
  }
}

// One LSTM step. 256x256 tile, BK=64, 8 waves (2Mx4N). Lagged-MFMA pipeline:
// per phase: [issue next quadrant's ds_reads] [issue one half-tile stage]
// [counted lgkmcnt -> only PREVIOUS phase's reads drained] [16 MFMA on
// resident frags] [vmcnt(4)] [barrier]. LDS reads drain UNDER the MFMA.
//
// Halves: h0=A-lo, h1=B-lo, h2=B-hi, h3=A-hi. Stage(kt,phase X) = half X of
// a tile 4 phases ahead; read(phase X) = half X of current tile. Guarantee
// chain (verified by hand, incl. tail): a half staged at phase P is drained
// by the vmcnt at end of P+2 (vmcnt(4) leaves the 2 newest halves) and read
// at P+4, with 2 barriers in between. Tail: stages stop after TILE(14).ph2,
// so TILE(14).ph4 needs vmcnt(2) and TILE(15).ph1 needs vmcnt(0).
// MFMA order per tile: Q00(al,bl) Q01(al,bh) Q11(ah,bh) Q10(ah,bl_old);
// bl register-double-buffered (blA/blB swap per tile, static names).
// Swizzle: verified scheme — 128B rows, byte ^= ((row&7)<<4), inverse
// pre-applied on the global source (0 conflicts measured R1/R2/R4).
__global__ __launch_bounds__(512, 2) void lstm_step(
    const __hip_bfloat16* __restrict__ hin,   // [4096][1024]
    const __hip_bfloat16* __restrict__ Bp,    // permuted Rt [4096][1024]
    const float* __restrict__ biasv,          // [4096] (orig layout)
    float* __restrict__ c,                    // [4096][1024] f32
    __hip_bfloat16* __restrict__ hout,        // [4096][1024]
    const float* __restrict__ dw,             // [1024]
    float* __restrict__ out, int t) {
  extern __shared__ char lds[];   // 131072 = 2 buf x (A 32K + B 32K)
  const int tid = threadIdx.x;
  const int lane = tid & 63;
  const int w = tid >> 6;
  const int l15 = lane & 15;
  const int lhi = lane >> 4;
  const int wr = w >> 2;          // 0..1
  const int wc = w & 3;           // 0..3

  // XCD-aware 4x8 rectangle mapping
  const int bi = blockIdx.x;
  const int xcd = bi & 7, slot = bi >> 3;
  const int bx = (xcd & 3) * 4 + (slot & 3);   // 0..15 (batch tiles)
  const int by = (xcd >> 2) * 8 + (slot >> 2); // 0..15 (unit tiles)

  const int ucol = by * 64 + wc * 16 + l15;
  const float dwv = dw[ucol];

  f32x4 acc[8][4];
#pragma unroll
  for (int g = 0; g < 4; ++g) {
    float bg = biasv[g * 1024 + ucol];
#pragma unroll
    for (int m = 0; m < 8; ++m) acc[m][g] = (f32x4){bg, bg, bg, bg};
  }
  // Anchor dwv NOW so its global load is complete before the staging loads
  // (keeps the counted-vmcnt ring exact).
  asm volatile("" :: "v"(dwv));

  const char* Asrc = (const char*)(hin + (size_t)bx * 256 * 1024);
  const char* Bsrc = (const char*)(Bp + (size_t)by * 256 * 1024);
  const int swz = (l15 & 7) << 4;   // read-side swizzle (row&7 == l15&7)

  // Stage one 128-row half (16 KB): 2 gload16/thread, linear LDS dest,
  // inverse-swizzled global source.
  auto STAGE = [&](const char* src, int rowoff, int kt, char* dstbase) {
#pragma unroll
    for (int i = 0; i < 2; ++i) {
      int chunk = i * 512 + tid;
      int row = chunk >> 3, s = chunk & 7;
      gload16(src + (size_t)(rowoff + row) * 2048 + kt * 128 +
                  ((s * 16) ^ ((row & 7) << 4)),
              dstbase + i * 8192 + w * 1024 + lane * 16);
    }
  };

  s16x8 al[4][2], ah[4][2], bh[2][2], blA[2][2], blB[2][2];

  auto RD_AL = [&](const char* Ab, s16x8 (&d)[4][2]) {
#pragma unroll
    for (int m = 0; m < 4; ++m) {
      int row = wr * 64 + m * 16 + l15;          // rows 0..127
#pragma unroll
      for (int kk = 0; kk < 2; ++kk)
        d[m][kk] = *(const s16x8*)(Ab + row * 128 + ((kk * 64 + lhi * 16) ^ swz));
    }
  };
  auto RD_AH = [&](const char* Ab, s16x8 (&d)[4][2]) {
#pragma unroll
    for (int m = 0; m < 4; ++m) {
      int row = 128 + wr * 64 + m * 16 + l15;    // rows 128..255
#pragma unroll
      for (int kk = 0; kk < 2; ++kk)
        d[m][kk] = *(const s16x8*)(Ab + row * 128 + ((kk * 64 + lhi * 16) ^ swz));
    }
  };
  auto RD_BL = [&](const char* Bb, s16x8 (&d)[2][2]) {
#pragma unroll
    for (int g = 0; g < 2; ++g) {
      int row = wc * 32 + g * 16 + l15;          // rows 0..127
#pragma unroll
      for (int kk = 0; kk < 2; ++kk)
        d[g][kk] = *(const s16x8*)(Bb + row * 128 + ((kk * 64 + lhi * 16) ^ swz));
    }
  };
  auto RD_BH = [&](const char* Bb, s16x8 (&d)[2][2]) {
#pragma unroll
    for (int g = 0; g < 2; ++g) {
      int row = 128 + wc * 32 + g * 16 + l15;    // rows 128..255
#pragma unroll
      for (int kk = 0; kk < 2; ++kk)
        d[g][kk] = *(const s16x8*)(Bb + row * 128 + ((kk * 64 + lhi * 16) ^ swz));
    }
  };

  // ---- prologue: tile0 all 4 halves + tile1 h0,h1 (12 loads), then
  // vmcnt(4) leaves exactly (1,h0),(1,h1) in flight -> tile0 guaranteed.
  STAGE(Asrc, 0,   0, lds);                       // (0,h0) A-lo
  STAGE(Bsrc, 0,   0, lds + 32768);               // (0,h1) B-lo
  STAGE(Bsrc, 128, 0, lds + 32768 + 16384);       // (0,h2) B-hi
  STAGE(Asrc, 128, 0, lds + 16384);               // (0,h3) A-hi
  STAGE(Asrc, 0,   1, lds + 65536);               // (1,h0)
  STAGE(Bsrc, 0,   1, lds + 65536 + 32768);       // (1,h1)
  asm volatile("s_waitcnt vmcnt(4)" ::: "memory");
  block_barrier();
  RD_AL(lds, al);            // al(0), 8 reads (in flight)
  RD_BL(lds + 32768, blA);   // bl(0), 4 reads (in flight)

  auto TILE = [&](int kt, s16x8 (&blCur)[2][2], s16x8 (&blNext)[2][2]) {
    const int p = kt & 1, q = p ^ 1;
    const char* Ab = lds + p * 65536;
    const char* Bb = Ab + 32768;
    char* SdN = lds + q * 65536;   // tile kt+1 halves (h2,h3)
    char* SdP = lds + p * 65536;   // tile kt+2 halves (h0,h1) — regions whose
                                   // tile-kt readers finished 4 phases ago

    // ---- phase 1 (h2): read B-hi(kt); stage (kt+1,h2); MFMA Q00
    RD_BH(Bb, bh);                                          // 4 reads
    if (kt < 15) STAGE(Bsrc, 128, kt + 1, SdN + 32768 + 16384);
    asm volatile("s_waitcnt lgkmcnt(4)" ::: "memory");      // al,blCur done
    __builtin_amdgcn_sched_barrier(0);
    MMA(al, blCur, 0, 0);
    if (kt == 15) asm volatile("s_waitcnt vmcnt(0)" ::: "memory");
    else          asm volatile("s_waitcnt vmcnt(4)" ::: "memory");
    block_barrier();

    // ---- phase 2 (h3): read A-hi(kt); stage (kt+1,h3); MFMA Q01
    RD_AH(Ab, ah);                                          // 8 reads
    if (kt < 15) STAGE(Asrc, 128, kt + 1, SdN + 16384);
    asm volatile("s_waitcnt lgkmcnt(8)" ::: "memory");      // bh done
    __builtin_amdgcn_sched_barrier(0);
    MMA(al, bh, 0, 2);
    asm volatile("s_waitcnt vmcnt(4)" ::: "memory");
    block_barrier();

    // ---- phase 3 (h0 of kt+1): read A-lo(kt+1); stage (kt+2,h0); MFMA Q11
    if (kt < 15) {
      RD_AL(SdN, al);                                       // 8 reads
      if (kt < 14) STAGE(Asrc, 0, kt + 2, SdP);
      asm volatile("s_waitcnt lgkmcnt(8)" ::: "memory");    // ah done
    } else {
      asm volatile("s_waitcnt lgkmcnt(0)" ::: "memory");
    }
    __builtin_amdgcn_sched_barrier(0);
    MMA(ah, bh, 4, 2);
    asm volatile("s_waitcnt vmcnt(4)" ::: "memory");
    block_barrier();

    // ---- phase 4 (h1 of kt+1): read B-lo(kt+1); stage (kt+2,h1); MFMA Q10
    if (kt < 15) {
      RD_BL(SdN + 32768, blNext);                           // 4 reads
      if (kt < 14) STAGE(Bsrc, 0, kt + 2, SdP + 32768);
      asm volatile("s_waitcnt lgkmcnt(4)" ::: "memory");    // ah (+old) done
    } else {
      asm volatile("s_waitcnt lgkmcnt(0)" ::: "memory");
    }
    __builtin_amdgcn_sched_barrier(0);
    MMA(ah, blCur, 4, 0);
    if (kt == 14) asm volatile("s_waitcnt vmcnt(2)" ::: "memory");
    else          asm volatile("s_waitcnt vmcnt(4)" ::: "memory");
    block_barrier();
  };

  for (int k2 = 0; k2 < 16; k2 += 2) {
    TILE(k2,     blA, blB);
    TILE(k2 + 1, blB, blA);
  }

  // ---- epilogue: gates, c/h update, fused pred partial-dot
  // A row map: row(m) = (m>>2)*128 + wr*64 + (m&3)*16 + l15
#pragma unroll
  for (int m = 0; m < 8; ++m) {
#pragma unroll
    for (int j = 0; j < 4; ++j) {
      int b = bx * 256 + (m >> 2) * 128 + wr * 64 + (m & 3) * 16 + lhi * 4 + j;
      size_t ci = (size_t)b * 1024 + ucol;
      float zi = acc[m][0][j], zf = acc[m][1][j];
      float zg = acc[m][2][j], zo = acc[m][3][j];
      float ig = fsigmoid(zi), fg = fsigmoid(zf);
      float gg = ftanh(zg), og = fsigmoid(zo);
      float cn = fg * c[ci] + ig * gg;
      c[ci] = cn;
      float hn = og * ftanh(cn);
      hout[ci] = __float2bfloat16(hn);
      float p = hn * dwv;
      p += __shfl_xor(p, 1);
      p += __shfl_xor(p, 2);
      p += __shfl_xor(p, 4);
      p += __shfl_xor(p, 8);
      if (l15 == 0) atomicAdd(&out[(size_t)b * NSTEP + t], p);
    }
  }
}

extern "C" void kernel_launch(void* const* d_in, const int* in_sizes, int n_in,
                              void* d_out, int out_size, void* d_ws, size_t ws_size,
                              hipStream_t stream) {
  const float* feat = (const float*)d_in[0];  // [4096][512]
  const float* ker  = (const float*)d_in[1];  // [1][4096]
  const float* R    = (const float*)d_in[2];  // [1024][4096]
  const float* bias = (const float*)d_in[3];  // [4096]
  const float* dw   = (const float*)d_in[4];  // [1024][1]
  const float* db   = (const float*)d_in[5];  // [1]
  float* out = (float*)d_out;

  char* ws = (char*)d_ws;
  const size_t MB = 1024 * 1024;
  __hip_bfloat16* Rt0 = (__hip_bfloat16*)(ws);            // 8 MB (permuted)
  __hip_bfloat16* Rt1 = (__hip_bfloat16*)(ws + 8 * MB);   // 8 MB (permuted+fold)
  float* bias1 = (float*)(ws + 16 * MB);                  // 16 KB
  __hip_bfloat16* hA = (__hip_bfloat16*)(ws + 16 * MB + 65536);  // 8 MB
  __hip_bfloat16* hB = (__hip_bfloat16*)(ws + 24 * MB + 65536);  // 8 MB
  float* cbuf = (float*)(ws + 32 * MB + 65536);           // 16 MB

  hipFuncSetAttribute((const void*)lstm_step,
                      hipFuncAttributeMaxDynamicSharedMemorySize, 131072);

  prep_weights<<<dim3(128, 32), dim3(32, 8), 0, stream>>>(R, ker, dw, Rt0, Rt1);
  prep_state<<<4096, 256, 0, stream>>>(feat, bias, ker, db, bias1, hA, cbuf, out);

  for (int t = 0; t < NSTEP; ++t) {
    const __hip_bfloat16* hin = (t & 1) ? hB : hA;
    __hip_bfloat16* hout = (t & 1) ? hA : hB;
    lstm_step<<<256, 512, 131072, stream>>>(
        hin, (t == 0) ? Rt0 : Rt1, (t == 0) ? bias : bias1, cbuf, hout, dw, out, t);
  }
}

// Round 8
// 6595.519 us; speedup vs baseline: 2.6156x; 2.6156x over previous
//
#include <hip/hip_runtime.h>
#include <hip/hip_bf16.h>
#include <stdint.h>

#define BATCH 4096
#define UNITS 1024
#define NSTEP 128

typedef __attribute__((ext_vector_type(4))) float f32x4;
typedef __attribute__((ext_vector_type(8))) short s16x8;

__device__ __forceinline__ void gload16(const void* g, void* l) {
  __builtin_amdgcn_global_load_lds(
      (const __attribute__((address_space(1))) unsigned int*)g,
      (__attribute__((address_space(3))) unsigned int*)l, 16, 0, 0);
}

__device__ __forceinline__ void block_barrier() {
  asm volatile("" ::: "memory");
  __builtin_amdgcn_s_barrier();
  asm volatile("" ::: "memory");
}

__device__ __forceinline__ float fsigmoid(float x) {
  return 1.0f / (1.0f + __expf(-x));
}
__device__ __forceinline__ float ftanh(float x) {
  return 1.0f - 2.0f / (__expf(2.0f * x) + 1.0f);
}

// 16-MFMA quadrant cluster; MO/GO must be literals (static acc indexing).
#define MMA(Afr, Bfr, MO, GO)                                              \
  do {                                                                     \
    __builtin_amdgcn_s_setprio(1);                                         \
    _Pragma("unroll") for (int m_ = 0; m_ < 4; ++m_)                       \
    _Pragma("unroll") for (int g_ = 0; g_ < 2; ++g_)                       \
    _Pragma("unroll") for (int k_ = 0; k_ < 2; ++k_)                       \
        acc[(MO) + m_][(GO) + g_] =                                        \
            __builtin_amdgcn_mfma_f32_16x16x32_bf16(                       \
                Afr[m_][k_], Bfr[g_][k_], acc[(MO) + m_][(GO) + g_],       \
                0, 0, 0);                                                  \
    __builtin_amdgcn_s_setprio(0);                                         \
  } while (0)

// Transpose recurrent_kernel [1024][4096] f32 -> permuted bf16 [4096][1024].
// orig n = g*1024 + u, u = q*64 + wc*16 + ul
//   -> n' = q*256 + (g>>1)*128 + wc*32 + (g&1)*16 + ul
// (gate-pair = contiguous 128-row staging half; gates lane-local in epilogue)
// Rt0 = plain R; Rt1 = R + dense_w (x) kernel (autoregressive fold).
__global__ void prep_weights(const float* __restrict__ R,
                             const float* __restrict__ ker,   // [4096]
                             const float* __restrict__ dw,    // [1024]
                             __hip_bfloat16* __restrict__ Rt0,
                             __hip_bfloat16* __restrict__ Rt1) {
  __shared__ float tile[32][33];
  __shared__ float dws[32];
  const int n0 = blockIdx.x * 32;
  const int k0 = blockIdx.y * 32;
  const int tx = threadIdx.x;       // 0..31
  const int ty = threadIdx.y;       // 0..7
#pragma unroll
  for (int i = 0; i < 4; ++i) {
    int k = ty + i * 8;
    tile[k][tx] = R[(size_t)(k0 + k) * 4096 + n0 + tx];
  }
  if (ty == 0) dws[tx] = dw[k0 + tx];
  __syncthreads();
#pragma unroll
  for (int i = 0; i < 4; ++i) {
    int n = ty + i * 8;
    float v = tile[tx][n];
    int gn = n0 + n, gk = k0 + tx;
    int g = gn >> 10, u = gn & 1023;
    int q = u >> 6, wc = (u >> 4) & 3, ul = u & 15;
    int np = q * 256 + (g >> 1) * 128 + wc * 32 + (g & 1) * 16 + ul;
    size_t o = (size_t)np * 1024 + gk;
    Rt0[o] = __float2bfloat16(v);
    Rt1[o] = __float2bfloat16(v + dws[tx] * ker[gn]);
  }
}

__global__ void prep_state(const float* __restrict__ feat,   // [4096][512]
                           const float* __restrict__ bias,   // [4096]
                           const float* __restrict__ ker,    // [4096]
                           const float* __restrict__ db,     // [1]
                           float* __restrict__ bias1,
                           __hip_bfloat16* __restrict__ hA,
                           float* __restrict__ c,
                           float* __restrict__ out) {
  const int total = BATCH * UNITS;
  const float dbv = db[0];
  for (int i = blockIdx.x * blockDim.x + threadIdx.x; i < total;
       i += gridDim.x * blockDim.x) {
    int b = i >> 10, u = i & 1023;
    float v = feat[b * 512 + (u & 511)];   // concat([features,features])
    hA[i] = __float2bfloat16(v);
    c[i] = v;
    if (i < 4096) bias1[i] = bias[i] + dbv * ker[i];
    if (i < BATCH * NSTEP) out[i] = dbv;
  }
}

// One LSTM step. 256x256 tile, BK=64, 8 waves (2Mx4N). m201-faithful 4-phase
// schedule: per phase {issue ds_reads; issue 1 half-tile stage; barrier;
// lgkmcnt(0); setprio(1); 16 MFMA; setprio(0); barrier}. Reads are issued
// BEFORE the entry barrier so they drain under other waves' MFMA; vmcnt(6)
// appears ONCE per K-tile (phase 4): distance-7-half stage ring.
//
// Halves (16 KB each): h0=A-lo, h1=B-lo, h2=B-hi, h3=A-hi.
// Read schedule for tile kt: ph1 reads h0(al)+h1(bl), ph2 reads h2(bh),
// ph3 reads h3(ah), ph4 none.  MFMA: ph1 Q00(al,bl), ph2 Q01(al,bh),
// ph3 Q11(ah,bh), ph4 Q10(ah,bl).  Frag live ranges within the tile only.
// Stage ring (7 halves ahead): kt.ph1 -> (kt+1,h3); kt.ph2 -> (kt+2,h0);
// kt.ph3 -> (kt+2,h1); kt.ph4 -> (kt+2,h2).  Boundary vmcnt(6) leaves only
// the 3 newest halves (all tile kt+2) in flight => tile kt+1 fully resident
// (vmcnt retires in order, m135). Region reuse: each stage overwrites a
// region whose readers passed an exit barrier >=1 phase earlier (checked
// per-half). Tail: no stages for tiles >15; kt==14 boundary needs vmcnt(0).
// Swizzle: verified scheme — 128B rows, byte ^= ((row&7)<<4), inverse
// pre-applied on the global source (0 conflicts measured R1/R2/R4).
__global__ __launch_bounds__(512, 2) void lstm_step(
    const __hip_bfloat16* __restrict__ hin,   // [4096][1024]
    const __hip_bfloat16* __restrict__ Bp,    // permuted Rt [4096][1024]
    const float* __restrict__ biasv,          // [4096] (orig layout)
    float* __restrict__ c,                    // [4096][1024] f32
    __hip_bfloat16* __restrict__ hout,        // [4096][1024]
    const float* __restrict__ dw,             // [1024]
    float* __restrict__ out, int t) {
  extern __shared__ char lds[];   // 131072 = 2 buf x (A 32K + B 32K)
  const int tid = threadIdx.x;
  const int lane = tid & 63;
  const int w = tid >> 6;
  const int l15 = lane & 15;
  const int lhi = lane >> 4;
  const int wr = w >> 2;          // 0..1
  const int wc = w & 3;           // 0..3

  // XCD-aware 4x8 rectangle mapping
  const int bi = blockIdx.x;
  const int xcd = bi & 7, slot = bi >> 3;
  const int bx = (xcd & 3) * 4 + (slot & 3);   // 0..15 (batch tiles)
  const int by = (xcd >> 2) * 8 + (slot >> 2); // 0..15 (unit tiles)

  const int ucol = by * 64 + wc * 16 + l15;
  const float dwv = dw[ucol];
  asm volatile("" :: "v"(dwv));   // force-issue before staging (vmcnt ring)

  f32x4 acc[8][4];
#pragma unroll
  for (int g = 0; g < 4; ++g) {
    float bg = biasv[g * 1024 + ucol];
    asm volatile("" :: "v"(bg));  // force-issue before staging
#pragma unroll
    for (int m = 0; m < 8; ++m) acc[m][g] = (f32x4){bg, bg, bg, bg};
  }

  const char* Asrc = (const char*)(hin + (size_t)bx * 256 * 1024);
  const char* Bsrc = (const char*)(Bp + (size_t)by * 256 * 1024);
  const int swz = (l15 & 7) << 4;   // read-side swizzle (row&7 == l15&7)

  // Stage one 128-row half (16 KB): 2 gload16/thread, linear LDS dest,
  // inverse-swizzled global source.
  auto STAGE = [&](const char* src, int rowoff, int kt, char* dstbase) {
#pragma unroll
    for (int i = 0; i < 2; ++i) {
      int chunk = i * 512 + tid;
      int row = chunk >> 3, s = chunk & 7;
      gload16(src + (size_t)(rowoff + row) * 2048 + kt * 128 +
                  ((s * 16) ^ ((row & 7) << 4)),
              dstbase + i * 8192 + w * 1024 + lane * 16);
    }
  };

  auto RD_AL = [&](const char* Ab, s16x8 (&d)[4][2]) {
#pragma unroll
    for (int m = 0; m < 4; ++m) {
      int row = wr * 64 + m * 16 + l15;          // rows 0..127
#pragma unroll
      for (int kk = 0; kk < 2; ++kk)
        d[m][kk] = *(const s16x8*)(Ab + row * 128 + ((kk * 64 + lhi * 16) ^ swz));
    }
  };
  auto RD_AH = [&](const char* Ab, s16x8 (&d)[4][2]) {
#pragma unroll
    for (int m = 0; m < 4; ++m) {
      int row = 128 + wr * 64 + m * 16 + l15;    // rows 128..255
#pragma unroll
      for (int kk = 0; kk < 2; ++kk)
        d[m][kk] = *(const s16x8*)(Ab + row * 128 + ((kk * 64 + lhi * 16) ^ swz));
    }
  };
  auto RD_BL = [&](const char* Bb, s16x8 (&d)[2][2]) {
#pragma unroll
    for (int g = 0; g < 2; ++g) {
      int row = wc * 32 + g * 16 + l15;          // rows 0..127
#pragma unroll
      for (int kk = 0; kk < 2; ++kk)
        d[g][kk] = *(const s16x8*)(Bb + row * 128 + ((kk * 64 + lhi * 16) ^ swz));
    }
  };
  auto RD_BH = [&](const char* Bb, s16x8 (&d)[2][2]) {
#pragma unroll
    for (int g = 0; g < 2; ++g) {
      int row = 128 + wc * 32 + g * 16 + l15;    // rows 128..255
#pragma unroll
      for (int kk = 0; kk < 2; ++kk)
        d[g][kk] = *(const s16x8*)(Bb + row * 128 + ((kk * 64 + lhi * 16) ^ swz));
    }
  };

  // ---- prologue: 7 halves in ring-age order, then vmcnt(6) => tile0 resident.
  STAGE(Asrc, 0,   0, lds);                           // (0,h0)
  STAGE(Bsrc, 0,   0, lds + 32768);                   // (0,h1)
  STAGE(Bsrc, 128, 0, lds + 32768 + 16384);           // (0,h2)
  STAGE(Asrc, 128, 0, lds + 16384);                   // (0,h3)
  STAGE(Asrc, 0,   1, lds + 65536);                   // (1,h0)
  STAGE(Bsrc, 0,   1, lds + 65536 + 32768);           // (1,h1)
  STAGE(Bsrc, 128, 1, lds + 65536 + 32768 + 16384);   // (1,h2)
  asm volatile("s_waitcnt vmcnt(6)" ::: "memory");
  block_barrier();

  for (int kt = 0; kt < 16; ++kt) {
    const int p = kt & 1, q = p ^ 1;
    const char* Ab = lds + p * 65536;
    const char* Bb = Ab + 32768;
    char* BufN = lds + q * 65536;   // parity kt+1 (h3 stage)
    char* BufP = lds + p * 65536;   // parity kt+2 == kt (h0,h1,h2 stages)

    s16x8 al[4][2], bl[2][2], bh[2][2], ah[4][2];

    // ---- ph1: issue al+bl reads (12); stage (kt+1,h3); bar; wait; Q00
    RD_AL(Ab, al);
    RD_BL(Bb, bl);
    if (kt + 1 <= 15) STAGE(Asrc, 128, kt + 1, BufN + 16384);
    asm volatile("s_waitcnt lgkmcnt(8)" ::: "memory");
    block_barrier();
    asm volatile("s_waitcnt lgkmcnt(0)" ::: "memory");
    __builtin_amdgcn_sched_barrier(0);
    MMA(al, bl, 0, 0);
    block_barrier();

    // ---- ph2: issue bh reads (4); stage (kt+2,h0); bar; wait; Q01
    RD_BH(Bb, bh);
    if (kt + 2 <= 15) STAGE(Asrc, 0, kt + 2, BufP);
    block_barrier();
    asm volatile("s_waitcnt lgkmcnt(0)" ::: "memory");
    __builtin_amdgcn_sched_barrier(0);
    MMA(al, bh, 0, 2);
    block_barrier();

    // ---- ph3: issue ah reads (8); stage (kt+2,h1); bar; wait; Q11
    RD_AH(Ab, ah);
    if (kt + 2 <= 15) STAGE(Bsrc, 0, kt + 2, BufP + 32768);
    block_barrier();
    asm volatile("s_waitcnt lgkmcnt(0)" ::: "memory");
    __builtin_amdgcn_sched_barrier(0);
    MMA(ah, bh, 4, 2);
    block_barrier();

    // ---- ph4: no reads; stage (kt+2,h2); bar; Q10; boundary vmcnt; bar
    if (kt + 2 <= 15) STAGE(Bsrc, 128, kt + 2, BufP + 32768 + 16384);
    block_barrier();
    MMA(ah, bl, 4, 0);
    if (kt < 14)       asm volatile("s_waitcnt vmcnt(6)" ::: "memory");
    else if (kt == 14) asm volatile("s_waitcnt vmcnt(0)" ::: "memory");
    block_barrier();
  }

  // ---- epilogue: gates, c/h update, fused pred partial-dot
  // A row map: row(m) = (m>>2)*128 + wr*64 + (m&3)*16 + l15
#pragma unroll
  for (int m = 0; m < 8; ++m) {
#pragma unroll
    for (int j = 0; j < 4; ++j) {
      int b = bx * 256 + (m >> 2) * 128 + wr * 64 + (m & 3) * 16 + lhi * 4 + j;
      size_t ci = (size_t)b * 1024 + ucol;
      float zi = acc[m][0][j], zf = acc[m][1][j];
      float zg = acc[m][2][j], zo = acc[m][3][j];
      float ig = fsigmoid(zi), fg = fsigmoid(zf);
      float gg = ftanh(zg), og = fsigmoid(zo);
      float cn = fg * c[ci] + ig * gg;
      c[ci] = cn;
      float hn = og * ftanh(cn);
      hout[ci] = __float2bfloat16(hn);
      float p = hn * dwv;
      p += __shfl_xor(p, 1);
      p += __shfl_xor(p, 2);
      p += __shfl_xor(p, 4);
      p += __shfl_xor(p, 8);
      if (l15 == 0) atomicAdd(&out[(size_t)b * NSTEP + t], p);
    }
  }
}

extern "C" void kernel_launch(void* const* d_in, const int* in_sizes, int n_in,
                              void* d_out, int out_size, void* d_ws, size_t ws_size,
                              hipStream_t stream) {
  const float* feat = (const float*)d_in[0];  // [4096][512]
  const float* ker  = (const float*)d_in[1];  // [1][4096]
  const float* R    = (const float*)d_in[2];  // [1024][4096]
  const float* bias = (const float*)d_in[3];  // [4096]
  const float* dw   = (const float*)d_in[4];  // [1024][1]
  const float* db   = (const float*)d_in[5];  // [1]
  float* out = (float*)d_out;

  char* ws = (char*)d_ws;
  const size_t MB = 1024 * 1024;
  __hip_bfloat16* Rt0 = (__hip_bfloat16*)(ws);            // 8 MB (permuted)
  __hip_bfloat16* Rt1 = (__hip_bfloat16*)(ws + 8 * MB);   // 8 MB (permuted+fold)
  float* bias1 = (float*)(ws + 16 * MB);                  // 16 KB
  __hip_bfloat16* hA = (__hip_bfloat16*)(ws + 16 * MB + 65536);  // 8 MB
  __hip_bfloat16* hB = (__hip_bfloat16*)(ws + 24 * MB + 65536);  // 8 MB
  float* cbuf = (float*)(ws + 32 * MB + 65536);           // 16 MB

  hipFuncSetAttribute((const void*)lstm_step,
                      hipFuncAttributeMaxDynamicSharedMemorySize, 131072);

  prep_weights<<<dim3(128, 32), dim3(32, 8), 0, stream>>>(R, ker, dw, Rt0, Rt1);
  prep_state<<<4096, 256, 0, stream>>>(feat, bias, ker, db, bias1, hA, cbuf, out);

  for (int t = 0; t < NSTEP; ++t) {
    const __hip_bfloat16* hin = (t & 1) ? hB : hA;
    __hip_bfloat16* hout = (t & 1) ? hA : hB;
    lstm_step<<<256, 512, 131072, stream>>>(
        hin, (t == 0) ? Rt0 : Rt1, (t == 0) ? bias : bias1, cbuf, hout, dw, out, t);
  }
}